// Round 9
// baseline (436.757 us; speedup 1.0000x reference)
//
#include <hip/hip_runtime.h>
#include <math.h>

#define Bq 2
#define Lq 2048
#define Eq 1024
#define Hq 16
#define Dq 64

typedef __attribute__((ext_vector_type(8))) short bf16x8;
typedef __attribute__((ext_vector_type(4))) short bf16x4;
typedef __attribute__((ext_vector_type(4))) float f32x4;

typedef __attribute__((address_space(1))) const void gconst_void;
typedef __attribute__((address_space(3))) void lds_void;
#define GLOAD_LDS16(g, l) \
    __builtin_amdgcn_global_load_lds((gconst_void*)(g), (lds_void*)(l), 16, 0, 0)

__device__ __forceinline__ short f2bf(float f) {
    union { float f; unsigned u; } x; x.f = f;
    unsigned r = x.u + 0x7FFFu + ((x.u >> 16) & 1u);
    return (short)(r >> 16);
}
__device__ __forceinline__ short f2bf_fast(float f) {  // round-half-up: 2 VALU ops
    union { float f; unsigned u; } x; x.f = f;
    return (short)((x.u + 0x8000u) >> 16);
}
__device__ __forceinline__ float bf2f(short s) {
    union { unsigned u; float f; } x;
    x.u = ((unsigned)(unsigned short)s) << 16;
    return x.f;
}

// Cast Q,K,V (4096x1024 f32) and Wq,Wk,Wv (1024x1024 f32) to bf16, laid out
// consecutively in `out`: [Xq | Xk | Xv | Wqb | Wkb | Wvb]. Tail blocks zero `os`.
__global__ __launch_bounds__(256) void cast_all(const float* __restrict__ Q,
                                                const float* __restrict__ K,
                                                const float* __restrict__ V,
                                                const float* __restrict__ Wq,
                                                const float* __restrict__ Wk,
                                                const float* __restrict__ Wv,
                                                short* __restrict__ out,
                                                float* __restrict__ os) {
    const size_t NX = (size_t)4096 * 1024 / 4;  // float4 count per X
    const size_t NW = (size_t)1024 * 1024 / 4;  // float4 count per W
    const size_t TOT = 3 * NX + 3 * NW;
    size_t id = (size_t)blockIdx.x * 256 + threadIdx.x;
    if (id >= TOT) {
        size_t z = id - TOT;
        if (z < (size_t)(Bq * Eq / 4)) {
            float4 zv = {0.f, 0.f, 0.f, 0.f};
            ((float4*)os)[z] = zv;
        }
        return;
    }
    const float* src; size_t off;
    if (id < NX)              { src = Q;  off = id; }
    else if (id < 2 * NX)     { src = K;  off = id - NX; }
    else if (id < 3 * NX)     { src = V;  off = id - 2 * NX; }
    else if (id < 3 * NX + NW)     { src = Wq; off = id - 3 * NX; }
    else if (id < 3 * NX + 2 * NW) { src = Wk; off = id - 3 * NX - NW; }
    else                           { src = Wv; off = id - 3 * NX - 2 * NW; }
    float4 v = ((const float4*)src)[off];
    bf16x4 s;
    s[0] = f2bf(v.x); s[1] = f2bf(v.y); s[2] = f2bf(v.z); s[3] = f2bf(v.w);
    ((bf16x4*)out)[id] = s;
}

// All three projections, m97-style LDS-staged GEMM.
// blockIdx.y = pidx*8 + ntile. Block tile 128(M)x128(N), BK=32, wave tile 64x64.
__global__ __launch_bounds__(256) void proj3_kernel(const short* __restrict__ castb,
                                                    short* __restrict__ qb,
                                                    short* __restrict__ kb,
                                                    short* __restrict__ vT,
                                                    float* __restrict__ q2,
                                                    float* __restrict__ k2) {
    const int wave = threadIdx.x >> 6;
    const int lane = threadIdx.x & 63;
    const int l15 = lane & 15, quad = lane >> 4;
    const int pidx = blockIdx.y >> 3;
    const short* Xb = castb + (size_t)pidx * 4096 * 1024;
    const short* Wb = castb + (size_t)3 * 4096 * 1024 + (size_t)pidx * 1024 * 1024;
    short* outb = (pidx == 0) ? qb : (pidx == 1) ? kb : vT;
    float* x2 = (pidx == 0) ? q2 : (pidx == 1) ? k2 : nullptr;
    const int transposed = (pidx == 2);
    const int m0 = blockIdx.x * 128;
    const int n0 = (blockIdx.y & 7) * 128;
    const int wm = wave & 1, wn = wave >> 1;

    __shared__ __align__(16) short lds_a[128 * 32];
    __shared__ __align__(16) short lds_b[128 * 32];

    const int srow = lane >> 2;
    const int scol = (lane & 3) * 8;
    const short* gA = Xb + (size_t)(m0 + wave * 16 + srow) * Eq + scol;
    const short* gB = Wb + (size_t)(n0 + wave * 16 + srow) * Eq + scol;
    short* la0 = lds_a + wave * 16 * 32;
    short* lb0 = lds_b + wave * 16 * 32;

    f32x4 acc[4][4] = {};

    for (int e0 = 0; e0 < Eq; e0 += 32) {
        __syncthreads();
        GLOAD_LDS16(gA + e0, la0);
        GLOAD_LDS16(gA + (size_t)64 * Eq + e0, la0 + 64 * 32);
        GLOAD_LDS16(gB + e0, lb0);
        GLOAD_LDS16(gB + (size_t)64 * Eq + e0, lb0 + 64 * 32);
        __syncthreads();

        bf16x8 af[4], bfr[4];
#pragma unroll
        for (int i = 0; i < 4; ++i)
            af[i] = *(const bf16x8*)(lds_a + (wm * 64 + i * 16 + l15) * 32 + quad * 8);
#pragma unroll
        for (int j = 0; j < 4; ++j)
            bfr[j] = *(const bf16x8*)(lds_b + (wn * 64 + j * 16 + l15) * 32 + quad * 8);
#pragma unroll
        for (int i = 0; i < 4; ++i)
#pragma unroll
            for (int j = 0; j < 4; ++j)
                acc[i][j] = __builtin_amdgcn_mfma_f32_16x16x32_bf16(af[i], bfr[j], acc[i][j], 0, 0, 0);
    }

    const int mw = m0 + wm * 64;
    const int nw = n0 + wn * 64;
    const int h = nw >> 6;
#pragma unroll
    for (int i = 0; i < 4; ++i) {
        float ss[4] = {0.f, 0.f, 0.f, 0.f};
#pragma unroll
        for (int r = 0; r < 4; ++r) {
            int tok = mw + i * 16 + quad * 4 + r;
            int b = tok >> 11, l = tok & 2047;
#pragma unroll
            for (int j = 0; j < 4; ++j) {
                int d = (nw + j * 16 + l15) & 63;
                short sb = f2bf(acc[i][j][r]);
                float sv = bf2f(sb);
                ss[r] += sv * sv;
                size_t idx = transposed
                                 ? (((size_t)(b * Hq + h) * Dq + d) * Lq + l)
                                 : (((size_t)(b * Hq + h) * Lq + l) * Dq + d);
                outb[idx] = sb;
            }
        }
        if (x2 != nullptr) {
#pragma unroll
            for (int r = 0; r < 4; ++r) {
#pragma unroll
                for (int off = 1; off < 16; off <<= 1) ss[r] += __shfl_xor(ss[r], off);
            }
            if (l15 == 0) {
#pragma unroll
                for (int r = 0; r < 4; ++r) {
                    int tok = mw + i * 16 + quad * 4 + r;
                    int b = tok >> 11, l = tok & 2047;
                    x2[(size_t)(b * Hq + h) * Lq + l] = ss[r];
                }
            }
        }
    }
}

// Pass A: flash partials, scores = -||q-k||, fixed softmax max = 0.
// Wave-private task, 16 q-rows per wave: wave w of block (bx,bh) handles
// q-tile qt = bx*2 + (w&1), key half ks = w>>1, 64 keys per iteration.
// No register K-prefetch (low VGPR -> 6 waves/SIMD); latency covered by TLP.
// Grid (64, B*H) = 2048 blocks, 256 threads.
__global__ __launch_bounds__(256, 6) void flash_part_kernel(const short* __restrict__ qb,
                                                            const short* __restrict__ kb,
                                                            const short* __restrict__ vT,
                                                            const float* __restrict__ q2,
                                                            const float* __restrict__ k2,
                                                            short* __restrict__ numpart,
                                                            float* __restrict__ denpart) {
    const int wave = threadIdx.x >> 6;
    const int lane = threadIdx.x & 63;
    const int l15 = lane & 15, quad = lane >> 4;
    const int bh = blockIdx.y;
    const int qt = blockIdx.x * 2 + (wave & 1);   // 16-row q tile, 0..127
    const int q0 = qt * 16;
    const int ks = wave >> 1;                     // key half
    const short* qbh = qb + (size_t)bh * Lq * Dq;
    const short* kbh = kb + (size_t)bh * Lq * Dq;
    const short* vbh = vT + (size_t)bh * Dq * Lq;
    const float* q2h = q2 + (size_t)bh * Lq;
    const float* k2h = k2 + (size_t)bh * Lq;

    // wave-private P transpose buffer: 16 rows x 64 key-cols, stride 72 shorts
    __shared__ __align__(16) short plds[4][16 * 72];
    short* pl = plds[wave];

    const short* qp = qbh + (size_t)(q0 + l15) * Dq + quad * 8;
    bf16x8 qf0 = *(const bf16x8*)qp;
    bf16x8 qf1 = *(const bf16x8*)(qp + 32);
    float q2r[4];
#pragma unroll
    for (int r = 0; r < 4; ++r) q2r[r] = q2h[q0 + quad * 4 + r];

    f32x4 o[4] = {};
    float lsum[4] = {0.f, 0.f, 0.f, 0.f};
    const int kbase = ks * (Lq / 2);

#pragma unroll 1
    for (int kc = 0; kc < Lq / 2; kc += 64) {
        const int k0 = kbase + kc;
        const short* kp = kbh + (size_t)(k0 + l15) * Dq + quad * 8;
        bf16x8 kfc[4][2];
        float k2c[4];
#pragma unroll
        for (int kt = 0; kt < 4; ++kt) {
            kfc[kt][0] = *(const bf16x8*)(kp + (size_t)kt * 16 * Dq);
            kfc[kt][1] = *(const bf16x8*)(kp + (size_t)kt * 16 * Dq + 32);
            k2c[kt] = k2h[k0 + kt * 16 + l15];
        }
        // S = q.k^T (4 ktiles)
        f32x4 s[4];
#pragma unroll
        for (int kt = 0; kt < 4; ++kt) {
            f32x4 z = {0.f, 0.f, 0.f, 0.f};
            z = __builtin_amdgcn_mfma_f32_16x16x32_bf16(qf0, kfc[kt][0], z, 0, 0, 0);
            z = __builtin_amdgcn_mfma_f32_16x16x32_bf16(qf1, kfc[kt][1], z, 0, 0, 0);
            s[kt] = z;
        }
        // V loads issued before the score VALU phase (latency hidden behind it)
        bf16x8 vf[2][4];
#pragma unroll
        for (int kc2 = 0; kc2 < 2; ++kc2)
#pragma unroll
            for (int f = 0; f < 4; ++f)
                vf[kc2][f] = *(const bf16x8*)(vbh + (size_t)(f * 16 + l15) * Lq +
                                              k0 + kc2 * 32 + quad * 8);
        // scores -> p = exp(-sqrt(d2)); lsum f32; P^T (bf16) to LDS
#pragma unroll
        for (int kt = 0; kt < 4; ++kt)
#pragma unroll
            for (int r = 0; r < 4; ++r) {
                float t = q2r[r] + k2c[kt];
                float d2 = fmaxf(fmaf(s[kt][r], -2.f, t), 0.f);
                float pv = __expf(-__builtin_amdgcn_sqrtf(d2));
                lsum[r] += pv;
                pl[(quad * 4 + r) * 72 + kt * 16 + l15] = f2bf_fast(pv);
            }
        // P (A-layout) from LDS, PV MFMAs
#pragma unroll
        for (int kc2 = 0; kc2 < 2; ++kc2) {
            bf16x8 pa = *(const bf16x8*)(pl + l15 * 72 + kc2 * 32 + quad * 8);
#pragma unroll
            for (int f = 0; f < 4; ++f)
                o[f] = __builtin_amdgcn_mfma_f32_16x16x32_bf16(pa, vf[kc2][f], o[f], 0, 0, 0);
        }
    }

    // reduce lsum over the 16 l15 lanes; write partials
#pragma unroll
    for (int r = 0; r < 4; ++r) {
#pragma unroll
        for (int off = 1; off < 16; off <<= 1) lsum[r] += __shfl_xor(lsum[r], off);
    }
    const size_t base = (((size_t)bh * 128 + qt) * 2 + ks) * 16;
    short* np_ = numpart + base * 64;
#pragma unroll
    for (int f = 0; f < 4; ++f)
#pragma unroll
        for (int r = 0; r < 4; ++r)
            np_[(quad * 4 + r) * 64 + f * 16 + l15] = f2bf(o[f][r]);
    if (l15 == 0) {
#pragma unroll
        for (int r = 0; r < 4; ++r) denpart[base + quad * 4 + r] = lsum[r];
    }
}

// Pass B: combine key-half partials, normalize per q-row, sum over q-rows.
// Grid 128: block = (bh, quarter of qtiles); atomicAdd into pre-zeroed osum.
__global__ __launch_bounds__(256) void combine_kernel(const short* __restrict__ numpart,
                                                      const float* __restrict__ denpart,
                                                      float* __restrict__ osum) {
    const int bh = blockIdx.x >> 2;
    const int qs = blockIdx.x & 3;
    const int d = threadIdx.x & 63;
    const int w2 = threadIdx.x >> 6;
    float acc = 0.f;
    for (int qt = qs * 32 + w2; qt < qs * 32 + 32; qt += 4) {
        const size_t b0 = ((size_t)bh * 128 + qt) * 32;  // ks=0 rows; ks=1 at +16
#pragma unroll
        for (int row = 0; row < 16; ++row) {
            float den = denpart[b0 + row] + denpart[b0 + 16 + row];
            float num = bf2f(numpart[(b0 + row) * 64 + d]) +
                        bf2f(numpart[(b0 + 16 + row) * 64 + d]);
            acc += num / den;
        }
    }
    __shared__ float red[256];
    red[threadIdx.x] = acc;
    __syncthreads();
    if (threadIdx.x < 64)
        atomicAdd(&osum[(size_t)bh * Dq + threadIdx.x],
                  red[threadIdx.x] + red[threadIdx.x + 64] +
                  red[threadIdx.x + 128] + red[threadIdx.x + 192]);
}

// out[b,j] = sum_e osum[b,e] * Wo[j,e]; one wave per output element
__global__ __launch_bounds__(256) void outproj_kernel(const float* __restrict__ osum,
                                                      const float* __restrict__ Wo,
                                                      float* __restrict__ out) {
    int idx = blockIdx.x * 4 + (threadIdx.x >> 6);
    int lane = threadIdx.x & 63;
    int b = idx >> 10, j = idx & 1023;
    const float* o = osum + (size_t)b * Eq;
    const float* w = Wo + (size_t)j * Eq;
    float4 s4 = {0.f, 0.f, 0.f, 0.f};
    for (int e = lane * 4; e < Eq; e += 256) {
        float4 ov = *(const float4*)(o + e);
        float4 wv = *(const float4*)(w + e);
        s4.x += ov.x * wv.x; s4.y += ov.y * wv.y;
        s4.z += ov.z * wv.z; s4.w += ov.w * wv.w;
    }
    float s = s4.x + s4.y + s4.z + s4.w;
#pragma unroll
    for (int off = 1; off < 64; off <<= 1) s += __shfl_xor(s, off);
    if (lane == 0) out[idx] = s;
}

extern "C" void kernel_launch(void* const* d_in, const int* in_sizes, int n_in,
                              void* d_out, int out_size, void* d_ws, size_t ws_size,
                              hipStream_t stream) {
    const float* Q  = (const float*)d_in[0];
    const float* K  = (const float*)d_in[1];
    const float* V  = (const float*)d_in[2];
    const float* Wq = (const float*)d_in[3];
    const float* Wk = (const float*)d_in[4];
    const float* Wv = (const float*)d_in[5];
    const float* Wo = (const float*)d_in[6];
    float* out = (float*)d_out;

    char* ws = (char*)d_ws;
    // [0,8M) qb | [8M,16M) kb | [16M,24M) vT | q2 | k2 | osum | [25M,55M) castb
    // numpart (16 MB) + denpart (512 KB) OVERLAY castb (dead after proj3).
    short* qb = (short*)ws;
    short* kb = (short*)(ws + (size_t)(8 << 20));
    short* vT = (short*)(ws + (size_t)(16 << 20));
    float* q2 = (float*)(ws + (size_t)(24 << 20));
    float* k2 = (float*)(ws + (size_t)(24 << 20) + (256 << 10));
    float* os = (float*)(ws + (size_t)(24 << 20) + (512 << 10));
    short* castb = (short*)(ws + (size_t)(25 << 20));
    short* numpart = (short*)(ws + (size_t)(25 << 20));           // 16 MB overlay
    float* denpart = (float*)(ws + (size_t)(41 << 20));           // 512 KB

    cast_all<<<15362, 256, 0, stream>>>(Q, K, V, Wq, Wk, Wv, castb, os);
    proj3_kernel<<<dim3(32, 24), 256, 0, stream>>>(castb, qb, kb, vT, q2, k2);
    flash_part_kernel<<<dim3(64, 32), 256, 0, stream>>>(qb, kb, vT, q2, k2, numpart, denpart);
    combine_kernel<<<128, 256, 0, stream>>>(numpart, denpart, os);
    outproj_kernel<<<512, 256, 0, stream>>>(os, Wo, out);
}

// Round 10
// 247.141 us; speedup vs baseline: 1.7672x; 1.7672x over previous
//
#include <hip/hip_runtime.h>
#include <math.h>

#define Bq 2
#define Lq 2048
#define Eq 1024
#define Hq 16
#define Dq 64

typedef __attribute__((ext_vector_type(8))) short bf16x8;
typedef __attribute__((ext_vector_type(4))) short bf16x4;
typedef __attribute__((ext_vector_type(4))) float f32x4;

typedef __attribute__((address_space(1))) const void gconst_void;
typedef __attribute__((address_space(3))) void lds_void;
#define GLOAD_LDS16(g, l) \
    __builtin_amdgcn_global_load_lds((gconst_void*)(g), (lds_void*)(l), 16, 0, 0)

__device__ __forceinline__ short f2bf(float f) {
    union { float f; unsigned u; } x; x.f = f;
    unsigned r = x.u + 0x7FFFu + ((x.u >> 16) & 1u);
    return (short)(r >> 16);
}
__device__ __forceinline__ short f2bf_fast(float f) {  // round-half-up: 2 VALU ops
    union { float f; unsigned u; } x; x.f = f;
    return (short)((x.u + 0x8000u) >> 16);
}
__device__ __forceinline__ float bf2f(short s) {
    union { unsigned u; float f; } x;
    x.u = ((unsigned)(unsigned short)s) << 16;
    return x.f;
}

// Cast Q,K,V (4096x1024 f32) and Wq,Wk,Wv (1024x1024 f32) to bf16, laid out
// consecutively in `out`: [Xq | Xk | Xv | Wqb | Wkb | Wvb]. Tail blocks zero `os`.
__global__ __launch_bounds__(256) void cast_all(const float* __restrict__ Q,
                                                const float* __restrict__ K,
                                                const float* __restrict__ V,
                                                const float* __restrict__ Wq,
                                                const float* __restrict__ Wk,
                                                const float* __restrict__ Wv,
                                                short* __restrict__ out,
                                                float* __restrict__ os) {
    const size_t NX = (size_t)4096 * 1024 / 4;  // float4 count per X
    const size_t NW = (size_t)1024 * 1024 / 4;  // float4 count per W
    const size_t TOT = 3 * NX + 3 * NW;
    size_t id = (size_t)blockIdx.x * 256 + threadIdx.x;
    if (id >= TOT) {
        size_t z = id - TOT;
        if (z < (size_t)(Bq * Eq / 4)) {
            float4 zv = {0.f, 0.f, 0.f, 0.f};
            ((float4*)os)[z] = zv;
        }
        return;
    }
    const float* src; size_t off;
    if (id < NX)              { src = Q;  off = id; }
    else if (id < 2 * NX)     { src = K;  off = id - NX; }
    else if (id < 3 * NX)     { src = V;  off = id - 2 * NX; }
    else if (id < 3 * NX + NW)     { src = Wq; off = id - 3 * NX; }
    else if (id < 3 * NX + 2 * NW) { src = Wk; off = id - 3 * NX - NW; }
    else                           { src = Wv; off = id - 3 * NX - 2 * NW; }
    float4 v = ((const float4*)src)[off];
    bf16x4 s;
    s[0] = f2bf(v.x); s[1] = f2bf(v.y); s[2] = f2bf(v.z); s[3] = f2bf(v.w);
    ((bf16x4*)out)[id] = s;
}

// All three projections, m97-style LDS-staged GEMM (unchanged from round 8).
__global__ __launch_bounds__(256) void proj3_kernel(const short* __restrict__ castb,
                                                    short* __restrict__ qb,
                                                    short* __restrict__ kb,
                                                    short* __restrict__ vT,
                                                    float* __restrict__ q2,
                                                    float* __restrict__ k2) {
    const int wave = threadIdx.x >> 6;
    const int lane = threadIdx.x & 63;
    const int l15 = lane & 15, quad = lane >> 4;
    const int pidx = blockIdx.y >> 3;
    const short* Xb = castb + (size_t)pidx * 4096 * 1024;
    const short* Wb = castb + (size_t)3 * 4096 * 1024 + (size_t)pidx * 1024 * 1024;
    short* outb = (pidx == 0) ? qb : (pidx == 1) ? kb : vT;
    float* x2 = (pidx == 0) ? q2 : (pidx == 1) ? k2 : nullptr;
    const int transposed = (pidx == 2);
    const int m0 = blockIdx.x * 128;
    const int n0 = (blockIdx.y & 7) * 128;
    const int wm = wave & 1, wn = wave >> 1;

    __shared__ __align__(16) short lds_a[128 * 32];
    __shared__ __align__(16) short lds_b[128 * 32];

    const int srow = lane >> 2;
    const int scol = (lane & 3) * 8;
    const short* gA = Xb + (size_t)(m0 + wave * 16 + srow) * Eq + scol;
    const short* gB = Wb + (size_t)(n0 + wave * 16 + srow) * Eq + scol;
    short* la0 = lds_a + wave * 16 * 32;
    short* lb0 = lds_b + wave * 16 * 32;

    f32x4 acc[4][4] = {};

    for (int e0 = 0; e0 < Eq; e0 += 32) {
        __syncthreads();
        GLOAD_LDS16(gA + e0, la0);
        GLOAD_LDS16(gA + (size_t)64 * Eq + e0, la0 + 64 * 32);
        GLOAD_LDS16(gB + e0, lb0);
        GLOAD_LDS16(gB + (size_t)64 * Eq + e0, lb0 + 64 * 32);
        __syncthreads();

        bf16x8 af[4], bfr[4];
#pragma unroll
        for (int i = 0; i < 4; ++i)
            af[i] = *(const bf16x8*)(lds_a + (wm * 64 + i * 16 + l15) * 32 + quad * 8);
#pragma unroll
        for (int j = 0; j < 4; ++j)
            bfr[j] = *(const bf16x8*)(lds_b + (wn * 64 + j * 16 + l15) * 32 + quad * 8);
#pragma unroll
        for (int i = 0; i < 4; ++i)
#pragma unroll
            for (int j = 0; j < 4; ++j)
                acc[i][j] = __builtin_amdgcn_mfma_f32_16x16x32_bf16(af[i], bfr[j], acc[i][j], 0, 0, 0);
    }

    const int mw = m0 + wm * 64;
    const int nw = n0 + wn * 64;
    const int h = nw >> 6;
#pragma unroll
    for (int i = 0; i < 4; ++i) {
        float ss[4] = {0.f, 0.f, 0.f, 0.f};
#pragma unroll
        for (int r = 0; r < 4; ++r) {
            int tok = mw + i * 16 + quad * 4 + r;
            int b = tok >> 11, l = tok & 2047;
#pragma unroll
            for (int j = 0; j < 4; ++j) {
                int d = (nw + j * 16 + l15) & 63;
                short sb = f2bf(acc[i][j][r]);
                float sv = bf2f(sb);
                ss[r] += sv * sv;
                size_t idx = transposed
                                 ? (((size_t)(b * Hq + h) * Dq + d) * Lq + l)
                                 : (((size_t)(b * Hq + h) * Lq + l) * Dq + d);
                outb[idx] = sb;
            }
        }
        if (x2 != nullptr) {
#pragma unroll
            for (int r = 0; r < 4; ++r) {
#pragma unroll
                for (int off = 1; off < 16; off <<= 1) ss[r] += __shfl_xor(ss[r], off);
            }
            if (l15 == 0) {
#pragma unroll
                for (int r = 0; r < 4; ++r) {
                    int tok = mw + i * 16 + quad * 4 + r;
                    int b = tok >> 11, l = tok & 2047;
                    x2[(size_t)(b * Hq + h) * Lq + l] = ss[r];
                }
            }
        }
    }
}

// Flash attention, scores = -||q-k||, fixed softmax max = 0.
// Block = 64 q-rows x one (b,h); wave w owns rows [q0+w*16, +16) over ALL 2048
// keys (no key split -> no partials pass). Per 64-key step, K (8KB) and V (8KB)
// tiles are staged block-cooperatively via coalesced loads + padded ds_write
// (conflict-free b128 fragment reads, ~8x fewer TA line-probes than per-lane
// fragment loads). Softmax state is wave-private; K/V LDS is read-only shared
// behind the 2-barrier pattern. Epilogue: in-wave normalize + q-reduce,
// 64 atomicAdds per wave into pre-zeroed osum.
// Grid (32, B*H) = 1024 blocks, 256 threads.
__global__ __launch_bounds__(256) void flash_kernel(const short* __restrict__ qb,
                                                    const short* __restrict__ kb,
                                                    const short* __restrict__ vT,
                                                    const float* __restrict__ q2,
                                                    const float* __restrict__ k2,
                                                    float* __restrict__ osum) {
    const int wave = threadIdx.x >> 6;
    const int lane = threadIdx.x & 63;
    const int l15 = lane & 15, quad = lane >> 4;
    const int bh = blockIdx.y;
    const int q0 = blockIdx.x * 64 + wave * 16;
    const short* qbh = qb + (size_t)bh * Lq * Dq;
    const short* kbh = kb + (size_t)bh * Lq * Dq;
    const short* vbh = vT + (size_t)bh * Dq * Lq;
    const float* q2h = q2 + (size_t)bh * Lq;
    const float* k2h = k2 + (size_t)bh * Lq;

    // Padded LDS tiles (stride 72 shorts = 144 B -> 4-bank shift/row, b128 reads
    // are 2-way-conflict-free). plds: wave-private P transpose.
    __shared__ __align__(16) short lds_k[64 * 72];
    __shared__ __align__(16) short lds_v[64 * 72];
    __shared__ __align__(16) short plds[4][16 * 72];
    short* pl = plds[wave];

    const short* qp = qbh + (size_t)(q0 + l15) * Dq + quad * 8;
    bf16x8 qf0 = *(const bf16x8*)qp;
    bf16x8 qf1 = *(const bf16x8*)(qp + 32);
    float q2r[4];
#pragma unroll
    for (int r = 0; r < 4; ++r) q2r[r] = q2h[q0 + quad * 4 + r];

    f32x4 o[4] = {};
    float lsum[4] = {0.f, 0.f, 0.f, 0.f};

#pragma unroll 1
    for (int k0 = 0; k0 < Lq; k0 += 64) {
        __syncthreads();
        // Stage K tile: keys k0..k0+63 are one contiguous 8KB block.
        {
            const short* src = kbh + (size_t)k0 * Dq;
#pragma unroll
            for (int rnd = 0; rnd < 2; ++rnd) {
                int idx = rnd * 256 + threadIdx.x;   // 0..511 : 16B chunks
                int key = idx >> 3, col = (idx & 7) * 8;
                bf16x8 tmp = *(const bf16x8*)(src + (size_t)idx * 8);
                *(bf16x8*)(lds_k + key * 72 + col) = tmp;
            }
            // Stage V tile: 64 d-rows x 64 keys, rows 128B contiguous (stride 4KB).
#pragma unroll
            for (int rnd = 0; rnd < 2; ++rnd) {
                int idx = rnd * 256 + threadIdx.x;
                int d = idx >> 3, col = (idx & 7) * 8;
                bf16x8 tmp = *(const bf16x8*)(vbh + (size_t)d * Lq + k0 + col);
                *(bf16x8*)(lds_v + d * 72 + col) = tmp;
            }
        }
        __syncthreads();

        float k2c[4];
#pragma unroll
        for (int kt = 0; kt < 4; ++kt) k2c[kt] = k2h[k0 + kt * 16 + l15];

        // S = q.k^T from LDS K fragments (conflict-free ds_read_b128)
        f32x4 s[4];
#pragma unroll
        for (int kt = 0; kt < 4; ++kt) {
            bf16x8 kf0 = *(const bf16x8*)(lds_k + (kt * 16 + l15) * 72 + quad * 8);
            bf16x8 kf1 = *(const bf16x8*)(lds_k + (kt * 16 + l15) * 72 + 32 + quad * 8);
            f32x4 z = {0.f, 0.f, 0.f, 0.f};
            z = __builtin_amdgcn_mfma_f32_16x16x32_bf16(qf0, kf0, z, 0, 0, 0);
            z = __builtin_amdgcn_mfma_f32_16x16x32_bf16(qf1, kf1, z, 0, 0, 0);
            s[kt] = z;
        }
        // scores -> p = exp(-sqrt(d2)); lsum; P^T (bf16) to wave-private LDS
#pragma unroll
        for (int kt = 0; kt < 4; ++kt)
#pragma unroll
            for (int r = 0; r < 4; ++r) {
                float t = q2r[r] + k2c[kt];
                float d2 = fmaxf(fmaf(s[kt][r], -2.f, t), 0.f);
                float pv = __expf(-__builtin_amdgcn_sqrtf(d2));
                lsum[r] += pv;
                pl[(quad * 4 + r) * 72 + kt * 16 + l15] = f2bf_fast(pv);
            }
        // P (A-layout) + V fragments from LDS, PV MFMAs
#pragma unroll
        for (int kc2 = 0; kc2 < 2; ++kc2) {
            bf16x8 pa = *(const bf16x8*)(pl + l15 * 72 + kc2 * 32 + quad * 8);
#pragma unroll
            for (int f = 0; f < 4; ++f) {
                bf16x8 vf = *(const bf16x8*)(lds_v + (f * 16 + l15) * 72 + kc2 * 32 + quad * 8);
                o[f] = __builtin_amdgcn_mfma_f32_16x16x32_bf16(pa, vf, o[f], 0, 0, 0);
            }
        }
    }

    // lsum: reduce over the 16 key-columns (l15 lanes); all lanes get totals
#pragma unroll
    for (int r = 0; r < 4; ++r) {
#pragma unroll
        for (int off = 1; off < 16; off <<= 1) lsum[r] += __shfl_xor(lsum[r], off);
    }
    // normalize rows, reduce over this wave's 16 q-rows, add into osum
#pragma unroll
    for (int f = 0; f < 4; ++f) {
        float cs = o[f][0] / lsum[0] + o[f][1] / lsum[1] +
                   o[f][2] / lsum[2] + o[f][3] / lsum[3];
        cs += __shfl_xor(cs, 16);
        cs += __shfl_xor(cs, 32);
        if (quad == 0) atomicAdd(&osum[(size_t)bh * Dq + f * 16 + l15], cs);
    }
}

// out[b,j] = sum_e osum[b,e] * Wo[j,e]; one wave per output element
__global__ __launch_bounds__(256) void outproj_kernel(const float* __restrict__ osum,
                                                      const float* __restrict__ Wo,
                                                      float* __restrict__ out) {
    int idx = blockIdx.x * 4 + (threadIdx.x >> 6);
    int lane = threadIdx.x & 63;
    int b = idx >> 10, j = idx & 1023;
    const float* o = osum + (size_t)b * Eq;
    const float* w = Wo + (size_t)j * Eq;
    float4 s4 = {0.f, 0.f, 0.f, 0.f};
    for (int e = lane * 4; e < Eq; e += 256) {
        float4 ov = *(const float4*)(o + e);
        float4 wv = *(const float4*)(w + e);
        s4.x += ov.x * wv.x; s4.y += ov.y * wv.y;
        s4.z += ov.z * wv.z; s4.w += ov.w * wv.w;
    }
    float s = s4.x + s4.y + s4.z + s4.w;
#pragma unroll
    for (int off = 1; off < 64; off <<= 1) s += __shfl_xor(s, off);
    if (lane == 0) out[idx] = s;
}

extern "C" void kernel_launch(void* const* d_in, const int* in_sizes, int n_in,
                              void* d_out, int out_size, void* d_ws, size_t ws_size,
                              hipStream_t stream) {
    const float* Q  = (const float*)d_in[0];
    const float* K  = (const float*)d_in[1];
    const float* V  = (const float*)d_in[2];
    const float* Wq = (const float*)d_in[3];
    const float* Wk = (const float*)d_in[4];
    const float* Wv = (const float*)d_in[5];
    const float* Wo = (const float*)d_in[6];
    float* out = (float*)d_out;

    char* ws = (char*)d_ws;
    // [0,8M) qb | [8M,16M) kb | [16M,24M) vT | q2 | k2 | osum | [25M,55M) castb
    short* qb = (short*)ws;
    short* kb = (short*)(ws + (size_t)(8 << 20));
    short* vT = (short*)(ws + (size_t)(16 << 20));
    float* q2 = (float*)(ws + (size_t)(24 << 20));
    float* k2 = (float*)(ws + (size_t)(24 << 20) + (256 << 10));
    float* os = (float*)(ws + (size_t)(24 << 20) + (512 << 10));
    short* castb = (short*)(ws + (size_t)(25 << 20));

    cast_all<<<15362, 256, 0, stream>>>(Q, K, V, Wq, Wk, Wv, castb, os);
    proj3_kernel<<<dim3(32, 24), 256, 0, stream>>>(castb, qb, kb, vT, q2, k2);
    flash_kernel<<<dim3(32, 32), 256, 0, stream>>>(qb, kb, vT, q2, k2, os);
    outproj_kernel<<<512, 256, 0, stream>>>(os, Wo, out);
}

// Round 11
// 230.720 us; speedup vs baseline: 1.8930x; 1.0712x over previous
//
#include <hip/hip_runtime.h>
#include <math.h>

#define Bq 2
#define Lq 2048
#define Eq 1024
#define Hq 16
#define Dq 64

typedef __attribute__((ext_vector_type(8))) short bf16x8;
typedef __attribute__((ext_vector_type(4))) short bf16x4;
typedef __attribute__((ext_vector_type(4))) float f32x4;

__device__ __forceinline__ short f2bf(float f) {
    union { float f; unsigned u; } x; x.f = f;
    unsigned r = x.u + 0x7FFFu + ((x.u >> 16) & 1u);
    return (short)(r >> 16);
}
__device__ __forceinline__ short f2bf_fast(float f) {  // round-half-up: 2 VALU ops
    union { float f; unsigned u; } x; x.f = f;
    return (short)((x.u + 0x8000u) >> 16);
}
__device__ __forceinline__ float bf2f(short s) {
    union { unsigned u; float f; } x;
    x.u = ((unsigned)(unsigned short)s) << 16;
    return x.f;
}

// Cast Q,K,V (4096x1024 f32) and Wq,Wk,Wv (1024x1024 f32) to bf16, laid out
// consecutively in `out`: [Xq | Xk | Xv | Wqb | Wkb | Wvb]. Tail blocks zero `os`.
__global__ __launch_bounds__(256) void cast_all(const float* __restrict__ Q,
                                                const float* __restrict__ K,
                                                const float* __restrict__ V,
                                                const float* __restrict__ Wq,
                                                const float* __restrict__ Wk,
                                                const float* __restrict__ Wv,
                                                short* __restrict__ out,
                                                float* __restrict__ os) {
    const size_t NX = (size_t)4096 * 1024 / 4;  // float4 count per X
    const size_t NW = (size_t)1024 * 1024 / 4;  // float4 count per W
    const size_t TOT = 3 * NX + 3 * NW;
    size_t id = (size_t)blockIdx.x * 256 + threadIdx.x;
    if (id >= TOT) {
        size_t z = id - TOT;
        if (z < (size_t)(Bq * Eq / 4)) {
            float4 zv = {0.f, 0.f, 0.f, 0.f};
            ((float4*)os)[z] = zv;
        }
        return;
    }
    const float* src; size_t off;
    if (id < NX)              { src = Q;  off = id; }
    else if (id < 2 * NX)     { src = K;  off = id - NX; }
    else if (id < 3 * NX)     { src = V;  off = id - 2 * NX; }
    else if (id < 3 * NX + NW)     { src = Wq; off = id - 3 * NX; }
    else if (id < 3 * NX + 2 * NW) { src = Wk; off = id - 3 * NX - NW; }
    else                           { src = Wv; off = id - 3 * NX - 2 * NW; }
    float4 v = ((const float4*)src)[off];
    bf16x4 s;
    s[0] = f2bf(v.x); s[1] = f2bf(v.y); s[2] = f2bf(v.z); s[3] = f2bf(v.w);
    ((bf16x4*)out)[id] = s;
}

// All three projections. Block tile 128x128, BK=32, wave tile 64x64.
// Manual staging into stride-40-padded LDS (b128 reads/writes at the 8-cycle
// uniform minimum: bank = (20*l15 + 4*quad) % 32) with register double-buffer:
// next K-slab's global loads are issued right after staging writes and consumed
// at the NEXT iteration's writes -> no exposed global latency between barriers.
__global__ __launch_bounds__(256) void proj3_kernel(const short* __restrict__ castb,
                                                    short* __restrict__ qb,
                                                    short* __restrict__ kb,
                                                    short* __restrict__ vT,
                                                    float* __restrict__ q2,
                                                    float* __restrict__ k2) {
    const int wave = threadIdx.x >> 6;
    const int lane = threadIdx.x & 63;
    const int l15 = lane & 15, quad = lane >> 4;
    const int pidx = blockIdx.y >> 3;
    const short* Xb = castb + (size_t)pidx * 4096 * 1024;
    const short* Wb = castb + (size_t)3 * 4096 * 1024 + (size_t)pidx * 1024 * 1024;
    short* outb = (pidx == 0) ? qb : (pidx == 1) ? kb : vT;
    float* x2 = (pidx == 0) ? q2 : (pidx == 1) ? k2 : nullptr;
    const int transposed = (pidx == 2);
    const int m0 = blockIdx.x * 128;
    const int n0 = (blockIdx.y & 7) * 128;
    const int wm = wave & 1, wn = wave >> 1;

    __shared__ __align__(16) short lds_a[128 * 40];
    __shared__ __align__(16) short lds_b[128 * 40];

    // staging: thread t covers 16B chunks t and t+256 of each 8KB (128x32) tile
    const int r0 = threadIdx.x >> 2;            // rows 0..63
    const int r1 = 64 + r0;                     // rows 64..127
    const int cc = (threadIdx.x & 3) * 8;       // col chunk (shorts)
    const short* gA0 = Xb + (size_t)(m0 + r0) * Eq + cc;
    const short* gA1 = Xb + (size_t)(m0 + r1) * Eq + cc;
    const short* gB0 = Wb + (size_t)(n0 + r0) * Eq + cc;
    const short* gB1 = Wb + (size_t)(n0 + r1) * Eq + cc;
    short* la0 = lds_a + r0 * 40 + cc;
    short* la1 = lds_a + r1 * 40 + cc;
    short* lb0 = lds_b + r0 * 40 + cc;
    short* lb1 = lds_b + r1 * 40 + cc;

    f32x4 acc[4][4] = {};
    bf16x8 pa0 = *(const bf16x8*)gA0;
    bf16x8 pa1 = *(const bf16x8*)gA1;
    bf16x8 pb0 = *(const bf16x8*)gB0;
    bf16x8 pb1 = *(const bf16x8*)gB1;

#pragma unroll 1
    for (int e0 = 0; e0 < Eq; e0 += 32) {
        __syncthreads();                 // all waves done reading previous slab
        *(bf16x8*)la0 = pa0; *(bf16x8*)la1 = pa1;
        *(bf16x8*)lb0 = pb0; *(bf16x8*)lb1 = pb1;
        if (e0 + 32 < Eq) {              // prefetch next slab (consumed next iter)
            pa0 = *(const bf16x8*)(gA0 + e0 + 32);
            pa1 = *(const bf16x8*)(gA1 + e0 + 32);
            pb0 = *(const bf16x8*)(gB0 + e0 + 32);
            pb1 = *(const bf16x8*)(gB1 + e0 + 32);
        }
        __syncthreads();                 // staging visible

        bf16x8 af[4], bfr[4];
#pragma unroll
        for (int i = 0; i < 4; ++i)
            af[i] = *(const bf16x8*)(lds_a + (wm * 64 + i * 16 + l15) * 40 + quad * 8);
#pragma unroll
        for (int j = 0; j < 4; ++j)
            bfr[j] = *(const bf16x8*)(lds_b + (wn * 64 + j * 16 + l15) * 40 + quad * 8);
#pragma unroll
        for (int i = 0; i < 4; ++i)
#pragma unroll
            for (int j = 0; j < 4; ++j)
                acc[i][j] = __builtin_amdgcn_mfma_f32_16x16x32_bf16(af[i], bfr[j], acc[i][j], 0, 0, 0);
    }

    const int mw = m0 + wm * 64;
    const int nw = n0 + wn * 64;
    const int h = nw >> 6;
#pragma unroll
    for (int i = 0; i < 4; ++i) {
        float ss[4] = {0.f, 0.f, 0.f, 0.f};
#pragma unroll
        for (int r = 0; r < 4; ++r) {
            int tok = mw + i * 16 + quad * 4 + r;
            int b = tok >> 11, l = tok & 2047;
#pragma unroll
            for (int j = 0; j < 4; ++j) {
                int d = (nw + j * 16 + l15) & 63;
                short sb = f2bf(acc[i][j][r]);
                float sv = bf2f(sb);
                ss[r] += sv * sv;
                size_t idx = transposed
                                 ? (((size_t)(b * Hq + h) * Dq + d) * Lq + l)
                                 : (((size_t)(b * Hq + h) * Lq + l) * Dq + d);
                outb[idx] = sb;
            }
        }
        if (x2 != nullptr) {
#pragma unroll
            for (int r = 0; r < 4; ++r) {
#pragma unroll
                for (int off = 1; off < 16; off <<= 1) ss[r] += __shfl_xor(ss[r], off);
            }
            if (l15 == 0) {
#pragma unroll
                for (int r = 0; r < 4; ++r) {
                    int tok = mw + i * 16 + quad * 4 + r;
                    int b = tok >> 11, l = tok & 2047;
                    x2[(size_t)(b * Hq + h) * Lq + l] = ss[r];
                }
            }
        }
    }
}

// Flash attention, scores = -||q-k||, fixed softmax max = 0.
// Block = 64 q-rows x one (b,h); wave w owns rows [q0+w*16, +16) over all keys.
// K/V tiles staged block-cooperatively into padded LDS with REGISTER PREFETCH:
// next tile's global loads issue right after this tile's ds_writes and land
// during the compute phase -> no exposed global latency between barriers.
// Grid (32, B*H) = 1024 blocks, 256 threads.
__global__ __launch_bounds__(256) void flash_kernel(const short* __restrict__ qb,
                                                    const short* __restrict__ kb,
                                                    const short* __restrict__ vT,
                                                    const float* __restrict__ q2,
                                                    const float* __restrict__ k2,
                                                    float* __restrict__ osum) {
    const int wave = threadIdx.x >> 6;
    const int lane = threadIdx.x & 63;
    const int l15 = lane & 15, quad = lane >> 4;
    const int bh = blockIdx.y;
    const int q0 = blockIdx.x * 64 + wave * 16;
    const short* qbh = qb + (size_t)bh * Lq * Dq;
    const short* kbh = kb + (size_t)bh * Lq * Dq;
    const short* vbh = vT + (size_t)bh * Dq * Lq;
    const float* q2h = q2 + (size_t)bh * Lq;
    const float* k2h = k2 + (size_t)bh * Lq;

    __shared__ __align__(16) short lds_k[64 * 72];
    __shared__ __align__(16) short lds_v[64 * 72];
    __shared__ __align__(16) short plds[4][16 * 72];
    short* pl = plds[wave];

    const short* qp = qbh + (size_t)(q0 + l15) * Dq + quad * 8;
    bf16x8 qf0 = *(const bf16x8*)qp;
    bf16x8 qf1 = *(const bf16x8*)(qp + 32);
    float q2r[4];
#pragma unroll
    for (int r = 0; r < 4; ++r) q2r[r] = q2h[q0 + quad * 4 + r];

    // staging geometry: thread t covers 16B chunks t and t+256 of each 8KB tile
    const int row0 = threadIdx.x >> 3;          // 0..31 (key row for K, d row for V)
    const int row1 = 32 + row0;
    const int sc = (threadIdx.x & 7) * 8;       // col chunk (shorts)
    short* lk0 = lds_k + row0 * 72 + sc;
    short* lk1 = lds_k + row1 * 72 + sc;
    short* lv0 = lds_v + row0 * 72 + sc;
    short* lv1 = lds_v + row1 * 72 + sc;

    f32x4 o[4] = {};
    float lsum[4] = {0.f, 0.f, 0.f, 0.f};

    // prologue: prefetch tile 0
    bf16x8 kp0 = *(const bf16x8*)(kbh + (size_t)(row0 * Dq) + sc * 8 / 8 + 0);
    // (K tile is contiguous: chunk c at kbh + k0*Dq + c*8; row0*Dq + sc == c*8)
    kp0 = *(const bf16x8*)(kbh + (size_t)row0 * Dq + sc);
    bf16x8 kp1 = *(const bf16x8*)(kbh + (size_t)row1 * Dq + sc);
    bf16x8 vp0 = *(const bf16x8*)(vbh + (size_t)row0 * Lq + sc);
    bf16x8 vp1 = *(const bf16x8*)(vbh + (size_t)row1 * Lq + sc);

#pragma unroll 1
    for (int k0 = 0; k0 < Lq; k0 += 64) {
        __syncthreads();                 // all waves done reading previous tile
        *(bf16x8*)lk0 = kp0; *(bf16x8*)lk1 = kp1;
        *(bf16x8*)lv0 = vp0; *(bf16x8*)lv1 = vp1;
        if (k0 + 64 < Lq) {              // prefetch next tile (consumed next iter)
            const short* ks = kbh + (size_t)(k0 + 64) * Dq;
            kp0 = *(const bf16x8*)(ks + (size_t)row0 * Dq + sc);
            kp1 = *(const bf16x8*)(ks + (size_t)row1 * Dq + sc);
            vp0 = *(const bf16x8*)(vbh + (size_t)row0 * Lq + k0 + 64 + sc);
            vp1 = *(const bf16x8*)(vbh + (size_t)row1 * Lq + k0 + 64 + sc);
        }
        __syncthreads();                 // staging visible

        float k2c[4];
#pragma unroll
        for (int kt = 0; kt < 4; ++kt) k2c[kt] = k2h[k0 + kt * 16 + l15];

        // S = q.k^T from LDS K fragments (uniform-bank ds_read_b128)
        f32x4 s[4];
#pragma unroll
        for (int kt = 0; kt < 4; ++kt) {
            bf16x8 kf0 = *(const bf16x8*)(lds_k + (kt * 16 + l15) * 72 + quad * 8);
            bf16x8 kf1 = *(const bf16x8*)(lds_k + (kt * 16 + l15) * 72 + 32 + quad * 8);
            f32x4 z = {0.f, 0.f, 0.f, 0.f};
            z = __builtin_amdgcn_mfma_f32_16x16x32_bf16(qf0, kf0, z, 0, 0, 0);
            z = __builtin_amdgcn_mfma_f32_16x16x32_bf16(qf1, kf1, z, 0, 0, 0);
            s[kt] = z;
        }
        // scores -> p = exp(-sqrt(d2)); lsum; P^T (bf16) to wave-private LDS
#pragma unroll
        for (int kt = 0; kt < 4; ++kt)
#pragma unroll
            for (int r = 0; r < 4; ++r) {
                float t = q2r[r] + k2c[kt];
                float d2 = fmaxf(fmaf(s[kt][r], -2.f, t), 0.f);
                float pv = __expf(-__builtin_amdgcn_sqrtf(d2));
                lsum[r] += pv;
                pl[(quad * 4 + r) * 72 + kt * 16 + l15] = f2bf_fast(pv);
            }
        // P (A-layout) + V fragments from LDS, PV MFMAs
#pragma unroll
        for (int kc2 = 0; kc2 < 2; ++kc2) {
            bf16x8 pa = *(const bf16x8*)(pl + l15 * 72 + kc2 * 32 + quad * 8);
#pragma unroll
            for (int f = 0; f < 4; ++f) {
                bf16x8 vf = *(const bf16x8*)(lds_v + (f * 16 + l15) * 72 + kc2 * 32 + quad * 8);
                o[f] = __builtin_amdgcn_mfma_f32_16x16x32_bf16(pa, vf, o[f], 0, 0, 0);
            }
        }
    }

    // lsum: reduce over the 16 key-columns (l15 lanes)
#pragma unroll
    for (int r = 0; r < 4; ++r) {
#pragma unroll
        for (int off = 1; off < 16; off <<= 1) lsum[r] += __shfl_xor(lsum[r], off);
    }
    // normalize rows, reduce over this wave's 16 q-rows, add into osum
#pragma unroll
    for (int f = 0; f < 4; ++f) {
        float cs = o[f][0] / lsum[0] + o[f][1] / lsum[1] +
                   o[f][2] / lsum[2] + o[f][3] / lsum[3];
        cs += __shfl_xor(cs, 16);
        cs += __shfl_xor(cs, 32);
        if (quad == 0) atomicAdd(&osum[(size_t)bh * Dq + f * 16 + l15], cs);
    }
}

// out[b,j] = sum_e osum[b,e] * Wo[j,e]; one wave per output element
__global__ __launch_bounds__(256) void outproj_kernel(const float* __restrict__ osum,
                                                      const float* __restrict__ Wo,
                                                      float* __restrict__ out) {
    int idx = blockIdx.x * 4 + (threadIdx.x >> 6);
    int lane = threadIdx.x & 63;
    int b = idx >> 10, j = idx & 1023;
    const float* o = osum + (size_t)b * Eq;
    const float* w = Wo + (size_t)j * Eq;
    float4 s4 = {0.f, 0.f, 0.f, 0.f};
    for (int e = lane * 4; e < Eq; e += 256) {
        float4 ov = *(const float4*)(o + e);
        float4 wv = *(const float4*)(w + e);
        s4.x += ov.x * wv.x; s4.y += ov.y * wv.y;
        s4.z += ov.z * wv.z; s4.w += ov.w * wv.w;
    }
    float s = s4.x + s4.y + s4.z + s4.w;
#pragma unroll
    for (int off = 1; off < 64; off <<= 1) s += __shfl_xor(s, off);
    if (lane == 0) out[idx] = s;
}

extern "C" void kernel_launch(void* const* d_in, const int* in_sizes, int n_in,
                              void* d_out, int out_size, void* d_ws, size_t ws_size,
                              hipStream_t stream) {
    const float* Q  = (const float*)d_in[0];
    const float* K  = (const float*)d_in[1];
    const float* V  = (const float*)d_in[2];
    const float* Wq = (const float*)d_in[3];
    const float* Wk = (const float*)d_in[4];
    const float* Wv = (const float*)d_in[5];
    const float* Wo = (const float*)d_in[6];
    float* out = (float*)d_out;

    char* ws = (char*)d_ws;
    // [0,8M) qb | [8M,16M) kb | [16M,24M) vT | q2 | k2 | osum | [25M,55M) castb
    short* qb = (short*)ws;
    short* kb = (short*)(ws + (size_t)(8 << 20));
    short* vT = (short*)(ws + (size_t)(16 << 20));
    float* q2 = (float*)(ws + (size_t)(24 << 20));
    float* k2 = (float*)(ws + (size_t)(24 << 20) + (256 << 10));
    float* os = (float*)(ws + (size_t)(24 << 20) + (512 << 10));
    short* castb = (short*)(ws + (size_t)(25 << 20));

    cast_all<<<15362, 256, 0, stream>>>(Q, K, V, Wq, Wk, Wv, castb, os);
    proj3_kernel<<<dim3(32, 24), 256, 0, stream>>>(castb, qb, kb, vT, q2, k2);
    flash_kernel<<<dim3(32, 32), 256, 0, stream>>>(qb, kb, vT, q2, k2, os);
    outproj_kernel<<<512, 256, 0, stream>>>(os, Wo, out);
}